// Round 4
// baseline (1028.746 us; speedup 1.0000x reference)
//
#include <hip/hip_runtime.h>
#include <hip/hip_bf16.h>

#define D 128
#define NBUCK_SHIFT 9

typedef __bf16 bf16x8 __attribute__((ext_vector_type(8)));
typedef float f32x4 __attribute__((ext_vector_type(4)));
typedef unsigned int u32x4 __attribute__((ext_vector_type(4)));
typedef unsigned short u16x4_t __attribute__((ext_vector_type(4)));
typedef unsigned short u16x8_t __attribute__((ext_vector_type(8)));

__device__ __forceinline__ float b2f(unsigned short u) {
    unsigned int x = ((unsigned int)u) << 16;
    return __builtin_bit_cast(float, x);
}
__device__ __forceinline__ unsigned short f2b(float f) {
    __hip_bfloat16 h = __float2bfloat16(f);
    return __builtin_bit_cast(unsigned short, h);
}

__device__ __forceinline__ void acc8(float* acc, u32x4 x) {
#pragma unroll
    for (int r = 0; r < 4; ++r) {
        acc[2 * r]     += __builtin_bit_cast(float, x[r] << 16);
        acc[2 * r + 1] += __builtin_bit_cast(float, x[r] & 0xffff0000u);
    }
}

// ---------------- CSR build ----------------
__global__ void hist_kernel(const int* __restrict__ dst, int* __restrict__ counts, int E) {
    int e = blockIdx.x * blockDim.x + threadIdx.x;
    if (e < E) atomicAdd(&counts[dst[e]], 1);
}

__global__ void block_sums_kernel(const int* __restrict__ counts, int* __restrict__ bsum, int N) {
    __shared__ int s[256];
    int b = blockIdx.x, t = threadIdx.x;
    int i0 = b * 1024 + t * 4;
    int v = 0;
#pragma unroll
    for (int j = 0; j < 4; ++j)
        if (i0 + j < N) v += counts[i0 + j];
    s[t] = v;
    __syncthreads();
    for (int off = 128; off > 0; off >>= 1) {
        if (t < off) s[t] += s[t + off];
        __syncthreads();
    }
    if (t == 0) bsum[b] = s[0];
}

__global__ void scan_kernel(const int* __restrict__ counts, const int* __restrict__ bsum,
                            int* __restrict__ row_ptr, int N, int nb, int E) {
    __shared__ int sb[128];
    __shared__ int sth[256];
    int b = blockIdx.x, t = threadIdx.x;
    if (t < nb) sb[t] = bsum[t];
    __syncthreads();
    if (t == 0) {
        int run = 0;
        for (int i = 0; i < nb; ++i) { int v = sb[i]; sb[i] = run; run += v; }
    }
    __syncthreads();
    int base = sb[b];
    int i0 = b * 1024 + t * 4;
    int c[4];
    int ls = 0;
#pragma unroll
    for (int j = 0; j < 4; ++j) {
        c[j] = (i0 + j < N) ? counts[i0 + j] : 0;
        ls += c[j];
    }
    sth[t] = ls;
    __syncthreads();
    for (int off = 1; off < 256; off <<= 1) {
        int v = (t >= off) ? sth[t - off] : 0;
        __syncthreads();
        sth[t] += v;
        __syncthreads();
    }
    int run = sth[t] - ls + base;
#pragma unroll
    for (int j = 0; j < 4; ++j) {
        if (i0 + j < N) row_ptr[i0 + j] = run;
        run += c[j];
    }
    if (b == 0 && t == 0) row_ptr[N] = E;
}

// Phase B: partition edges into dst-bucket-grouped (src,dst) pairs.
// Bucket b's region in `pairs` is [row_ptr[b*512], row_ptr[(b+1)*512]) — contiguous runs
// per block per bucket -> write traffic ~E*8B instead of E*64B.
__global__ __launch_bounds__(256) void bucket_kernel(
        const int* __restrict__ src, const int* __restrict__ dst,
        const int* __restrict__ row_ptr, int* __restrict__ bcursor,
        int2* __restrict__ pairs, int E, int nbuck) {
    __shared__ int lcnt[256];
    __shared__ int lbase[256];
    int t = threadIdx.x;
    int base = blockIdx.x * 4096;
    if (t < nbuck) lcnt[t] = 0;
    __syncthreads();
    int d[16], s[16];
#pragma unroll
    for (int k = 0; k < 16; ++k) {
        int i = base + t + k * 256;
        if (i < E) {
            d[k] = dst[i];
            s[k] = src[i];
            atomicAdd(&lcnt[d[k] >> NBUCK_SHIFT], 1);
        } else {
            d[k] = -1;
            s[k] = 0;
        }
    }
    __syncthreads();
    if (t < nbuck) {
        int c = lcnt[t];
        int g = (c > 0) ? atomicAdd(&bcursor[t], c) : 0;
        lbase[t] = row_ptr[t << NBUCK_SHIFT] + g;
        lcnt[t] = 0;
    }
    __syncthreads();
#pragma unroll
    for (int k = 0; k < 16; ++k) {
        if (d[k] >= 0) {
            int b = d[k] >> NBUCK_SHIFT;
            int r = atomicAdd(&lcnt[b], 1);
            pairs[lbase[b] + r] = make_int2(s[k], d[k]);
        }
    }
}

// Phase C: scatter within buckets. Each block owns a contiguous pair-chunk, so its
// random col writes are confined to ~1 bucket's 32KB window (L2-resident).
__global__ __launch_bounds__(256) void scatter2_kernel(
        const int2* __restrict__ pairs, const int* __restrict__ row_ptr,
        int* __restrict__ cursor, int* __restrict__ col, int E, int chunk) {
    int base = blockIdx.x * chunk;
    int end = min(base + chunk, E);
    for (int i = base + threadIdx.x; i < end; i += 256) {
        int2 p = pairs[i];
        int slot = row_ptr[p.y] + atomicAdd(&cursor[p.y], 1);
        col[slot] = p.x;
    }
}

// ---------------- dtype conversion ----------------
__global__ void f32_to_bf16_kernel(const float4* __restrict__ in, ushort4* __restrict__ out, int n4) {
    int i = blockIdx.x * blockDim.x + threadIdx.x;
    if (i < n4) {
        float4 f = in[i];
        ushort4 o;
        o.x = f2b(f.x); o.y = f2b(f.y); o.z = f2b(f.z); o.w = f2b(f.w);
        out[i] = o;
    }
}

// W[l][k][n] row-major -> frag-blocked bf16 for use as MFMA A-operand (swapped GEMM):
// flat short idx = ((l*32 + nt*4 + kb)*64 + lg*16 + l15)*8 + j holds W[k=kb*32+lg*8+j][n=nt*16+l15]
__global__ void wtrans_kernel(const float* __restrict__ W1, const float* __restrict__ W2,
                              unsigned short* __restrict__ W1L, unsigned short* __restrict__ W2L,
                              int total) {
    int i = blockIdx.x * blockDim.x + threadIdx.x;
    if (i < total) {
        int l = i >> 14;
        int rem = i & 16383;
        int k = rem >> 7;
        int n = rem & 127;
        int nt = n >> 4, l15 = n & 15;
        int kb = k >> 5, lg = (k >> 3) & 3, j = k & 7;
        int o = ((l * 32 + nt * 4 + kb) * 64 + lg * 16 + l15) * 8 + j;
        W1L[o] = f2b(W1[i]);
        W2L[o] = f2b(W2[i]);
    }
}

// ---------------- aggregation: rst[v] = h[v] + sum_{(u->v)} h[u] ----------------
// one wave per node; lane = j*16+i: i = feature block (8 bf16, 16B), j = edge slot.
__global__ __launch_bounds__(256) void agg_kernel(
        const unsigned short* __restrict__ h, const int* __restrict__ row_ptr,
        const int* __restrict__ col, unsigned short* __restrict__ rst, int N) {
    int lane = threadIdx.x & 63;
    int i = lane & 15;
    int j = lane >> 4;
    int v = blockIdx.x * 4 + (threadIdx.x >> 6);
    if (v >= N) return;

    int e0 = row_ptr[v], e1 = row_ptr[v + 1];

    float accA[8], accB[8];
#pragma unroll
    for (int r = 0; r < 8; ++r) { accA[r] = 0.f; accB[r] = 0.f; }

    if (j == 0) {
        u32x4 x = *(const u32x4*)(h + (size_t)v * D + i * 8);
        acc8(accA, x);
    }

    int e = e0 + j;
    for (; e + 4 < e1; e += 8) {
        int u0 = col[e];
        int u1 = col[e + 4];
        u32x4 x0 = *(const u32x4*)(h + (size_t)u0 * D + i * 8);
        u32x4 x1 = *(const u32x4*)(h + (size_t)u1 * D + i * 8);
        acc8(accA, x0);
        acc8(accB, x1);
    }
    if (e < e1) {
        u32x4 x0 = *(const u32x4*)(h + (size_t)col[e] * D + i * 8);
        acc8(accA, x0);
    }

    unsigned short outv[8];
#pragma unroll
    for (int r = 0; r < 8; ++r) {
        float s = accA[r] + accB[r];
        s += __shfl_xor(s, 16);
        s += __shfl_xor(s, 32);
        outv[r] = f2b(s);
    }
    if (j == 0) {
        u16x8_t o;
#pragma unroll
        for (int r = 0; r < 8; ++r) o[r] = outv[r];
        *(u16x8_t*)(rst + (size_t)v * D + i * 8) = o;
    }
}

// ---------------- fused MLP: h_out = [relu](([relu](rst@W1+b1)) @ W2 + b2) ----------------
// Swapped MFMA GEMMs (W as A-operand); h1 round-trips through a per-wave padded LDS tile.
// Padded tile unit U(m,k) = (k/32)*80 + m*5 + (k%32)/8; shorts at U*8.
__global__ __launch_bounds__(256, 4) void mlp_kernel(
        const unsigned short* __restrict__ A, const unsigned short* __restrict__ W1L,
        const unsigned short* __restrict__ W2L, const float* __restrict__ b1,
        const float* __restrict__ b2, unsigned short* __restrict__ hOut,
        float* __restrict__ fOut, int mode, int ntiles, int N) {
    __shared__ float b1s[128], b2s[128];
    __shared__ unsigned short tilebuf[4 * 2560];
    int tid = threadIdx.x;
    if (tid < 128) b1s[tid] = b1[tid];
    else b2s[tid - 128] = b2[tid - 128];
    __syncthreads();
    int wave = tid >> 6, lane = tid & 63, l15 = lane & 15, lg = lane >> 4;
    unsigned short* buf = tilebuf + wave * 2560;
    int stride = gridDim.x * 4;
    for (int tile = blockIdx.x * 4 + wave; tile < ntiles; tile += stride) {
        int v0 = tile << 4;
        // B-frags of rst straight from global (row-major): lane l15 = node, lg = k-octet
        bf16x8 bfrag[4];
        const unsigned short* arow = A + (size_t)(v0 + l15) * D + lg * 8;
#pragma unroll
        for (int kb = 0; kb < 4; ++kb) bfrag[kb] = *(const bf16x8*)(arow + kb * 32);

        f32x4 acc[8];
#pragma unroll
        for (int nt = 0; nt < 8; ++nt) acc[nt] = (f32x4){0.f, 0.f, 0.f, 0.f};
#pragma unroll
        for (int kb = 0; kb < 4; ++kb)
#pragma unroll
            for (int nt = 0; nt < 8; ++nt) {
                bf16x8 wf = *(const bf16x8*)(W1L + ((nt * 4 + kb) * 64 + lane) * 8);
                acc[nt] = __builtin_amdgcn_mfma_f32_16x16x32_bf16(wf, bfrag[kb], acc[nt], 0, 0, 0);
            }
        // h1[m=l15][n1=nt*16+lg*4+r] -> LDS tile
#pragma unroll
        for (int nt = 0; nt < 8; ++nt) {
            f32x4 bias = *(const f32x4*)(b1s + nt * 16 + lg * 4);
            int kb2 = nt >> 1;
            int lgk = (nt & 1) * 2 + (lg >> 1);
            int U = kb2 * 80 + l15 * 5 + lgk;
            u16x4_t o;
#pragma unroll
            for (int r = 0; r < 4; ++r) {
                float x = acc[nt][r] + bias[r];
                if (mode == 0) x = fmaxf(x, 0.f);
                o[r] = f2b(x);
            }
            *(u16x4_t*)(buf + U * 8 + (lg & 1) * 4) = o;
        }
        // reload h1 as B-frags
        bf16x8 bf2[4];
#pragma unroll
        for (int kb = 0; kb < 4; ++kb)
            bf2[kb] = *(const bf16x8*)(buf + (kb * 80 + l15 * 5 + lg) * 8);
#pragma unroll
        for (int nt = 0; nt < 8; ++nt) acc[nt] = (f32x4){0.f, 0.f, 0.f, 0.f};
#pragma unroll
        for (int kb = 0; kb < 4; ++kb)
#pragma unroll
            for (int nt = 0; nt < 8; ++nt) {
                bf16x8 wf = *(const bf16x8*)(W2L + ((nt * 4 + kb) * 64 + lane) * 8);
                acc[nt] = __builtin_amdgcn_mfma_f32_16x16x32_bf16(wf, bf2[kb], acc[nt], 0, 0, 0);
            }
        int m = v0 + l15;
        if (m < N) {
#pragma unroll
            for (int nt = 0; nt < 8; ++nt) {
                f32x4 bias = *(const f32x4*)(b2s + nt * 16 + lg * 4);
                int c0 = nt * 16 + lg * 4;
                if (mode == 0) {
                    u16x4_t o;
#pragma unroll
                    for (int r = 0; r < 4; ++r) o[r] = f2b(fmaxf(acc[nt][r] + bias[r], 0.f));
                    *(u16x4_t*)(hOut + (size_t)m * D + c0) = o;
                } else {
                    f32x4 o;
#pragma unroll
                    for (int r = 0; r < 4; ++r) o[r] = acc[nt][r] + bias[r];
                    *(f32x4*)(fOut + (size_t)m * D + c0) = o;
                }
            }
        }
    }
}

extern "C" void kernel_launch(void* const* d_in, const int* in_sizes, int n_in,
                              void* d_out, int out_size, void* d_ws, size_t ws_size,
                              hipStream_t stream) {
    const float* feat = (const float*)d_in[0];
    const float* W1 = (const float*)d_in[1];
    const float* b1 = (const float*)d_in[2];
    const float* W2 = (const float*)d_in[3];
    const float* b2 = (const float*)d_in[4];
    const int* src = (const int*)d_in[5];
    const int* dst = (const int*)d_in[6];

    const int N = in_sizes[0] / D;
    const int L = in_sizes[2] / D;
    const int E = in_sizes[5];

    char* w = (char*)d_ws;
    size_t off = 0;
    auto alloc = [&](size_t bytes) {
        void* p = w + off;
        off = (off + bytes + 255) & ~(size_t)255;
        return p;
    };
    unsigned short* bufA = (unsigned short*)alloc((size_t)N * D * 2);
    unsigned short* bufB = (unsigned short*)alloc((size_t)N * D * 2);
    // bufR (agg output) and pairs (CSR build scratch) share a region: disjoint lifetimes
    size_t unionBytes = (size_t)N * D * 2;
    if ((size_t)E * 8 > unionBytes) unionBytes = (size_t)E * 8;
    unsigned short* bufR = (unsigned short*)alloc(unionBytes);
    int2* pairs = (int2*)bufR;
    int* col = (int*)alloc((size_t)E * 4);
    int* row_ptr = (int*)alloc((size_t)(N + 1) * 4);
    int* counts = (int*)alloc((size_t)(N + 256) * 4);  // counts/cursor + bucket cursors
    int* bcursor = counts + N;
    unsigned short* W1L = (unsigned short*)alloc((size_t)L * 16384 * 2);
    unsigned short* W2L = (unsigned short*)alloc((size_t)L * 16384 * 2);
    int* bsum = (int*)alloc(512);

    int nb = (N + 1023) / 1024;
    int nbuck = (N + 511) >> NBUCK_SHIFT;

    // CSR build
    hipMemsetAsync(counts, 0, (size_t)(N + 256) * 4, stream);
    hist_kernel<<<(E + 255) / 256, 256, 0, stream>>>(dst, counts, E);
    block_sums_kernel<<<nb, 256, 0, stream>>>(counts, bsum, N);
    scan_kernel<<<nb, 256, 0, stream>>>(counts, bsum, row_ptr, N, nb, E);
    hipMemsetAsync(counts, 0, (size_t)N * 4, stream);
    bucket_kernel<<<(E + 4095) / 4096, 256, 0, stream>>>(src, dst, row_ptr, bcursor, pairs, E, nbuck);
    int chunk = (E + 511) / 512;
    scatter2_kernel<<<512, 256, 0, stream>>>(pairs, row_ptr, counts, col, E, chunk);

    // dtype prep
    int n4 = N * D / 4;
    f32_to_bf16_kernel<<<(n4 + 255) / 256, 256, 0, stream>>>((const float4*)feat, (ushort4*)bufA, n4);
    int wtotal = L * D * D;
    wtrans_kernel<<<(wtotal + 255) / 256, 256, 0, stream>>>(W1, W2, W1L, W2L, wtotal);

    int ntiles = (N + 15) / 16;
    int aggBlocks = (N + 3) / 4;
    int mlpGrid = (ntiles + 3) / 4;
    const unsigned short* hin[3] = {bufA, bufB, bufA};
    unsigned short* hout[3] = {bufB, bufA, nullptr};
    for (int i = 0; i < L; ++i) {
        int mode = (i == L - 1) ? 1 : 0;
        agg_kernel<<<aggBlocks, 256, 0, stream>>>(hin[i], row_ptr, col, bufR, N);
        mlp_kernel<<<mlpGrid, 256, 0, stream>>>(bufR, W1L + (size_t)i * 16384, W2L + (size_t)i * 16384,
                                                b1 + i * D, b2 + i * D, hout[i], (float*)d_out,
                                                mode, ntiles, N);
    }
}

// Round 5
// 535.190 us; speedup vs baseline: 1.9222x; 1.9222x over previous
//
#include <hip/hip_runtime.h>
#include <hip/hip_bf16.h>

#define D 128
#define NBUCK_SHIFT 9

typedef __bf16 bf16x8 __attribute__((ext_vector_type(8)));
typedef float f32x4 __attribute__((ext_vector_type(4)));
typedef unsigned int u32x4 __attribute__((ext_vector_type(4)));
typedef unsigned short u16x4_t __attribute__((ext_vector_type(4)));
typedef unsigned short u16x8_t __attribute__((ext_vector_type(8)));

__device__ __forceinline__ float b2f(unsigned short u) {
    unsigned int x = ((unsigned int)u) << 16;
    return __builtin_bit_cast(float, x);
}
__device__ __forceinline__ unsigned short f2b(float f) {
    __hip_bfloat16 h = __float2bfloat16(f);
    return __builtin_bit_cast(unsigned short, h);
}

__device__ __forceinline__ void acc8(float* acc, u32x4 x) {
#pragma unroll
    for (int r = 0; r < 4; ++r) {
        acc[2 * r]     += __builtin_bit_cast(float, x[r] << 16);
        acc[2 * r + 1] += __builtin_bit_cast(float, x[r] & 0xffff0000u);
    }
}

// ---------------- CSR build ----------------
__global__ void hist_kernel(const int* __restrict__ dst, int* __restrict__ counts, int E) {
    int e = blockIdx.x * blockDim.x + threadIdx.x;
    if (e < E) atomicAdd(&counts[dst[e]], 1);
}

__global__ void block_sums_kernel(const int* __restrict__ counts, int* __restrict__ bsum, int N) {
    __shared__ int s[256];
    int b = blockIdx.x, t = threadIdx.x;
    int i0 = b * 1024 + t * 4;
    int v = 0;
#pragma unroll
    for (int j = 0; j < 4; ++j)
        if (i0 + j < N) v += counts[i0 + j];
    s[t] = v;
    __syncthreads();
    for (int off = 128; off > 0; off >>= 1) {
        if (t < off) s[t] += s[t + off];
        __syncthreads();
    }
    if (t == 0) bsum[b] = s[0];
}

__global__ void scan_kernel(const int* __restrict__ counts, const int* __restrict__ bsum,
                            int* __restrict__ row_ptr, int N, int nb, int E) {
    __shared__ int sb[128];
    __shared__ int sth[256];
    int b = blockIdx.x, t = threadIdx.x;
    if (t < nb) sb[t] = bsum[t];
    __syncthreads();
    if (t == 0) {
        int run = 0;
        for (int i = 0; i < nb; ++i) { int v = sb[i]; sb[i] = run; run += v; }
    }
    __syncthreads();
    int base = sb[b];
    int i0 = b * 1024 + t * 4;
    int c[4];
    int ls = 0;
#pragma unroll
    for (int j = 0; j < 4; ++j) {
        c[j] = (i0 + j < N) ? counts[i0 + j] : 0;
        ls += c[j];
    }
    sth[t] = ls;
    __syncthreads();
    for (int off = 1; off < 256; off <<= 1) {
        int v = (t >= off) ? sth[t - off] : 0;
        __syncthreads();
        sth[t] += v;
        __syncthreads();
    }
    int run = sth[t] - ls + base;
#pragma unroll
    for (int j = 0; j < 4; ++j) {
        if (i0 + j < N) row_ptr[i0 + j] = run;
        run += c[j];
    }
    if (b == 0 && t == 0) row_ptr[N] = E;
}

// Phase B: partition edges into dst-bucket-grouped (src,dst) pairs.
__global__ __launch_bounds__(256) void bucket_kernel(
        const int* __restrict__ src, const int* __restrict__ dst,
        const int* __restrict__ row_ptr, int* __restrict__ bcursor,
        int2* __restrict__ pairs, int E, int nbuck) {
    __shared__ int lcnt[256];
    __shared__ int lbase[256];
    int t = threadIdx.x;
    int base = blockIdx.x * 4096;
    if (t < nbuck) lcnt[t] = 0;
    __syncthreads();
    int d[16], s[16];
#pragma unroll
    for (int k = 0; k < 16; ++k) {
        int i = base + t + k * 256;
        if (i < E) {
            d[k] = dst[i];
            s[k] = src[i];
            atomicAdd(&lcnt[d[k] >> NBUCK_SHIFT], 1);
        } else {
            d[k] = -1;
            s[k] = 0;
        }
    }
    __syncthreads();
    if (t < nbuck) {
        int c = lcnt[t];
        int g = (c > 0) ? atomicAdd(&bcursor[t], c) : 0;
        lbase[t] = row_ptr[t << NBUCK_SHIFT] + g;
        lcnt[t] = 0;
    }
    __syncthreads();
#pragma unroll
    for (int k = 0; k < 16; ++k) {
        if (d[k] >= 0) {
            int b = d[k] >> NBUCK_SHIFT;
            int r = atomicAdd(&lcnt[b], 1);
            pairs[lbase[b] + r] = make_int2(s[k], d[k]);
        }
    }
}

// Phase C: scatter within buckets (col writes confined to L2-resident windows).
__global__ __launch_bounds__(256) void scatter2_kernel(
        const int2* __restrict__ pairs, const int* __restrict__ row_ptr,
        int* __restrict__ cursor, int* __restrict__ col, int E, int chunk) {
    int base = blockIdx.x * chunk;
    int end = min(base + chunk, E);
    for (int i = base + threadIdx.x; i < end; i += 256) {
        int2 p = pairs[i];
        int slot = row_ptr[p.y] + atomicAdd(&cursor[p.y], 1);
        col[slot] = p.x;
    }
}

// ---------------- dtype conversion ----------------
__global__ void f32_to_bf16_kernel(const float4* __restrict__ in, ushort4* __restrict__ out, int n4) {
    int i = blockIdx.x * blockDim.x + threadIdx.x;
    if (i < n4) {
        float4 f = in[i];
        ushort4 o;
        o.x = f2b(f.x); o.y = f2b(f.y); o.z = f2b(f.z); o.w = f2b(f.w);
        out[i] = o;
    }
}

// W[l][k][n] row-major -> frag-blocked bf16 for use as MFMA A-operand (swapped GEMM):
// flat short idx = ((l*32 + nt*4 + kb)*64 + lg*16 + l15)*8 + j holds W[k=kb*32+lg*8+j][n=nt*16+l15]
__global__ void wtrans_kernel(const float* __restrict__ W1, const float* __restrict__ W2,
                              unsigned short* __restrict__ W1L, unsigned short* __restrict__ W2L,
                              int total) {
    int i = blockIdx.x * blockDim.x + threadIdx.x;
    if (i < total) {
        int l = i >> 14;
        int rem = i & 16383;
        int k = rem >> 7;
        int n = rem & 127;
        int nt = n >> 4, l15 = n & 15;
        int kb = k >> 5, lg = (k >> 3) & 3, j = k & 7;
        int o = ((l * 32 + nt * 4 + kb) * 64 + lg * 16 + l15) * 8 + j;
        W1L[o] = f2b(W1[i]);
        W2L[o] = f2b(W2[i]);
    }
}

// ---------------- aggregation: rst[v] = h[v] + sum_{(u->v)} h[u] ----------------
// one wave per node; lane = j*16+i: i = feature block (8 bf16, 16B), j = edge slot.
// 4 independent acc chains -> up to 16 edges (64B/lane) in flight per iteration.
__global__ __launch_bounds__(256) void agg_kernel(
        const unsigned short* __restrict__ h, const int* __restrict__ row_ptr,
        const int* __restrict__ col, unsigned short* __restrict__ rst, int N) {
    int lane = threadIdx.x & 63;
    int i = lane & 15;
    int j = lane >> 4;
    int v = blockIdx.x * 4 + (threadIdx.x >> 6);
    if (v >= N) return;

    const unsigned short* hb = h + i * 8;
    int e0 = row_ptr[v], e1 = row_ptr[v + 1];

    float accA[8], accB[8], accC[8], accD[8];
#pragma unroll
    for (int r = 0; r < 8; ++r) { accA[r] = 0.f; accB[r] = 0.f; accC[r] = 0.f; accD[r] = 0.f; }

    if (j == 0) {
        u32x4 x = *(const u32x4*)(hb + (size_t)v * D);
        acc8(accA, x);
    }

    int e = e0 + j;
    for (; e + 12 < e1; e += 16) {
        int u0 = col[e];
        int u1 = col[e + 4];
        int u2 = col[e + 8];
        int u3 = col[e + 12];
        u32x4 x0 = *(const u32x4*)(hb + (size_t)u0 * D);
        u32x4 x1 = *(const u32x4*)(hb + (size_t)u1 * D);
        u32x4 x2 = *(const u32x4*)(hb + (size_t)u2 * D);
        u32x4 x3 = *(const u32x4*)(hb + (size_t)u3 * D);
        acc8(accA, x0);
        acc8(accB, x1);
        acc8(accC, x2);
        acc8(accD, x3);
    }
    for (; e + 4 < e1; e += 8) {
        int u0 = col[e];
        int u1 = col[e + 4];
        u32x4 x0 = *(const u32x4*)(hb + (size_t)u0 * D);
        u32x4 x1 = *(const u32x4*)(hb + (size_t)u1 * D);
        acc8(accA, x0);
        acc8(accB, x1);
    }
    if (e < e1) {
        u32x4 x0 = *(const u32x4*)(hb + (size_t)col[e] * D);
        acc8(accA, x0);
    }

    unsigned short outv[8];
#pragma unroll
    for (int r = 0; r < 8; ++r) {
        float s = (accA[r] + accB[r]) + (accC[r] + accD[r]);
        s += __shfl_xor(s, 16);
        s += __shfl_xor(s, 32);
        outv[r] = f2b(s);
    }
    if (j == 0) {
        u16x8_t o;
#pragma unroll
        for (int r = 0; r < 8; ++r) o[r] = outv[r];
        *(u16x8_t*)(rst + (size_t)v * D + i * 8) = o;
    }
}

// ---------------- fused MLP: one 16-node tile per wave (NO tile loop -> no spill) ----------------
// Swapped MFMA GEMMs (W frag-blocked in global as A-operand); h1 via per-wave padded LDS tile.
// Padded tile unit U(m,k) = (k/32)*80 + m*5 + (k%32)/8; shorts at U*8.
__global__ __launch_bounds__(256, 4) void mlp_kernel(
        const unsigned short* __restrict__ A, const unsigned short* __restrict__ W1L,
        const unsigned short* __restrict__ W2L, const float* __restrict__ b1,
        const float* __restrict__ b2, unsigned short* __restrict__ hOut,
        float* __restrict__ fOut, int mode, int ntiles, int N) {
    __shared__ float b1s[128], b2s[128];
    __shared__ unsigned short tilebuf[4 * 2560];
    int tid = threadIdx.x;
    if (tid < 128) b1s[tid] = b1[tid];
    else b2s[tid - 128] = b2[tid - 128];
    __syncthreads();
    int wave = tid >> 6, lane = tid & 63, l15 = lane & 15, lg = lane >> 4;
    unsigned short* buf = tilebuf + wave * 2560;
    int tile = blockIdx.x * 4 + wave;
    if (tile >= ntiles) return;
    int v0 = tile << 4;

    // B-frags of rst straight from global (row-major): lane l15 = node, lg = k-octet
    bf16x8 bfrag[4];
    const unsigned short* arow = A + (size_t)(v0 + l15) * D + lg * 8;
#pragma unroll
    for (int kb = 0; kb < 4; ++kb) bfrag[kb] = *(const bf16x8*)(arow + kb * 32);

    f32x4 acc[8];
#pragma unroll
    for (int nt = 0; nt < 8; ++nt) acc[nt] = (f32x4){0.f, 0.f, 0.f, 0.f};
#pragma unroll
    for (int kb = 0; kb < 4; ++kb)
#pragma unroll
        for (int nt = 0; nt < 8; ++nt) {
            bf16x8 wf = *(const bf16x8*)(W1L + ((nt * 4 + kb) * 64 + lane) * 8);
            acc[nt] = __builtin_amdgcn_mfma_f32_16x16x32_bf16(wf, bfrag[kb], acc[nt], 0, 0, 0);
        }
    // h1[m=l15][n1=nt*16+lg*4+r] -> LDS tile
#pragma unroll
    for (int nt = 0; nt < 8; ++nt) {
        f32x4 bias = *(const f32x4*)(b1s + nt * 16 + lg * 4);
        int kb2 = nt >> 1;
        int lgk = (nt & 1) * 2 + (lg >> 1);
        int U = kb2 * 80 + l15 * 5 + lgk;
        u16x4_t o;
#pragma unroll
        for (int r = 0; r < 4; ++r) {
            float x = acc[nt][r] + bias[r];
            if (mode == 0) x = fmaxf(x, 0.f);
            o[r] = f2b(x);
        }
        *(u16x4_t*)(buf + U * 8 + (lg & 1) * 4) = o;
    }
    // reload h1 as B-frags
    bf16x8 bf2[4];
#pragma unroll
    for (int kb = 0; kb < 4; ++kb)
        bf2[kb] = *(const bf16x8*)(buf + (kb * 80 + l15 * 5 + lg) * 8);
#pragma unroll
    for (int nt = 0; nt < 8; ++nt) acc[nt] = (f32x4){0.f, 0.f, 0.f, 0.f};
#pragma unroll
    for (int kb = 0; kb < 4; ++kb)
#pragma unroll
        for (int nt = 0; nt < 8; ++nt) {
            bf16x8 wf = *(const bf16x8*)(W2L + ((nt * 4 + kb) * 64 + lane) * 8);
            acc[nt] = __builtin_amdgcn_mfma_f32_16x16x32_bf16(wf, bf2[kb], acc[nt], 0, 0, 0);
        }
    int m = v0 + l15;
    if (m < N) {
#pragma unroll
        for (int nt = 0; nt < 8; ++nt) {
            f32x4 bias = *(const f32x4*)(b2s + nt * 16 + lg * 4);
            int c0 = nt * 16 + lg * 4;
            if (mode == 0) {
                u16x4_t o;
#pragma unroll
                for (int r = 0; r < 4; ++r) o[r] = f2b(fmaxf(acc[nt][r] + bias[r], 0.f));
                *(u16x4_t*)(hOut + (size_t)m * D + c0) = o;
            } else {
                f32x4 o;
#pragma unroll
                for (int r = 0; r < 4; ++r) o[r] = acc[nt][r] + bias[r];
                *(f32x4*)(fOut + (size_t)m * D + c0) = o;
            }
        }
    }
}

extern "C" void kernel_launch(void* const* d_in, const int* in_sizes, int n_in,
                              void* d_out, int out_size, void* d_ws, size_t ws_size,
                              hipStream_t stream) {
    const float* feat = (const float*)d_in[0];
    const float* W1 = (const float*)d_in[1];
    const float* b1 = (const float*)d_in[2];
    const float* W2 = (const float*)d_in[3];
    const float* b2 = (const float*)d_in[4];
    const int* src = (const int*)d_in[5];
    const int* dst = (const int*)d_in[6];

    const int N = in_sizes[0] / D;
    const int L = in_sizes[2] / D;
    const int E = in_sizes[5];

    char* w = (char*)d_ws;
    size_t off = 0;
    auto alloc = [&](size_t bytes) {
        void* p = w + off;
        off = (off + bytes + 255) & ~(size_t)255;
        return p;
    };
    unsigned short* bufA = (unsigned short*)alloc((size_t)N * D * 2);
    unsigned short* bufB = (unsigned short*)alloc((size_t)N * D * 2);
    size_t unionBytes = (size_t)N * D * 2;
    if ((size_t)E * 8 > unionBytes) unionBytes = (size_t)E * 8;
    unsigned short* bufR = (unsigned short*)alloc(unionBytes);
    int2* pairs = (int2*)bufR;
    int* col = (int*)alloc((size_t)E * 4);
    int* row_ptr = (int*)alloc((size_t)(N + 1) * 4);
    int* counts = (int*)alloc((size_t)(N + 256) * 4);
    int* bcursor = counts + N;
    unsigned short* W1L = (unsigned short*)alloc((size_t)L * 16384 * 2);
    unsigned short* W2L = (unsigned short*)alloc((size_t)L * 16384 * 2);
    int* bsum = (int*)alloc(512);

    int nb = (N + 1023) / 1024;
    int nbuck = (N + 511) >> NBUCK_SHIFT;

    hipMemsetAsync(counts, 0, (size_t)(N + 256) * 4, stream);
    hist_kernel<<<(E + 255) / 256, 256, 0, stream>>>(dst, counts, E);
    block_sums_kernel<<<nb, 256, 0, stream>>>(counts, bsum, N);
    scan_kernel<<<nb, 256, 0, stream>>>(counts, bsum, row_ptr, N, nb, E);
    hipMemsetAsync(counts, 0, (size_t)N * 4, stream);
    bucket_kernel<<<(E + 4095) / 4096, 256, 0, stream>>>(src, dst, row_ptr, bcursor, pairs, E, nbuck);
    int chunk = (E + 511) / 512;
    scatter2_kernel<<<512, 256, 0, stream>>>(pairs, row_ptr, counts, col, E, chunk);

    int n4 = N * D / 4;
    f32_to_bf16_kernel<<<(n4 + 255) / 256, 256, 0, stream>>>((const float4*)feat, (ushort4*)bufA, n4);
    int wtotal = L * D * D;
    wtrans_kernel<<<(wtotal + 255) / 256, 256, 0, stream>>>(W1, W2, W1L, W2L, wtotal);

    int ntiles = (N + 15) / 16;
    int aggBlocks = (N + 3) / 4;
    int mlpGrid = (ntiles + 3) / 4;
    const unsigned short* hin[3] = {bufA, bufB, bufA};
    unsigned short* hout[3] = {bufB, bufA, nullptr};
    for (int i = 0; i < L; ++i) {
        int mode = (i == L - 1) ? 1 : 0;
        agg_kernel<<<aggBlocks, 256, 0, stream>>>(hin[i], row_ptr, col, bufR, N);
        mlp_kernel<<<mlpGrid, 256, 0, stream>>>(bufR, W1L + (size_t)i * 16384, W2L + (size_t)i * 16384,
                                                b1 + i * D, b2 + i * D, hout[i], (float*)d_out,
                                                mode, ntiles, N);
    }
}

// Round 6
// 447.918 us; speedup vs baseline: 2.2967x; 1.1948x over previous
//
#include <hip/hip_runtime.h>
#include <hip/hip_bf16.h>

#define D 128
#define NBUCK_SHIFT 9

typedef __bf16 bf16x8 __attribute__((ext_vector_type(8)));
typedef float f32x4 __attribute__((ext_vector_type(4)));
typedef unsigned int u32x4 __attribute__((ext_vector_type(4)));
typedef unsigned short u16x4_t __attribute__((ext_vector_type(4)));
typedef unsigned short u16x8_t __attribute__((ext_vector_type(8)));

__device__ __forceinline__ float b2f(unsigned short u) {
    unsigned int x = ((unsigned int)u) << 16;
    return __builtin_bit_cast(float, x);
}
__device__ __forceinline__ unsigned short f2b(float f) {
    __hip_bfloat16 h = __float2bfloat16(f);
    return __builtin_bit_cast(unsigned short, h);
}

__device__ __forceinline__ void acc8(float* acc, u32x4 x) {
#pragma unroll
    for (int r = 0; r < 4; ++r) {
        acc[2 * r]     += __builtin_bit_cast(float, x[r] << 16);
        acc[2 * r + 1] += __builtin_bit_cast(float, x[r] & 0xffff0000u);
    }
}

// ---------------- CSR build (bucket-local, no per-node global atomics) ----------------
// Phase A: coarse histogram over nbuck (<=256) dst-buckets, LDS-aggregated.
__global__ __launch_bounds__(256) void coarse_hist_kernel(
        const int* __restrict__ dst, int* __restrict__ bco, int E, int nbuck) {
    __shared__ int s[256];
    int t = threadIdx.x;
    s[t] = 0;
    __syncthreads();
    for (int i = blockIdx.x * 256 + t; i < E; i += gridDim.x * 256)
        atomicAdd(&s[dst[i] >> NBUCK_SHIFT], 1);
    __syncthreads();
    if (t < nbuck && s[t] > 0) atomicAdd(&bco[t], s[t]);
}

// Phase B: exclusive scan of bucket counts -> bbase[0..nbuck], bbase[nbuck]=E. One block.
__global__ __launch_bounds__(256) void bucket_scan_kernel(
        const int* __restrict__ bco, int* __restrict__ bbase, int nbuck, int E) {
    __shared__ int s[256];
    int t = threadIdx.x;
    int c = (t < nbuck) ? bco[t] : 0;
    s[t] = c;
    __syncthreads();
    for (int o = 1; o < 256; o <<= 1) {
        int y = (t >= o) ? s[t - o] : 0;
        __syncthreads();
        s[t] += y;
        __syncthreads();
    }
    if (t < nbuck) bbase[t] = s[t] - c;
    if (t == 0) bbase[nbuck] = E;
}

// Phase C: partition edges into dst-bucket-grouped (src,dst) pairs.
__global__ __launch_bounds__(256) void bucket_kernel(
        const int* __restrict__ src, const int* __restrict__ dst,
        const int* __restrict__ bbase, int* __restrict__ bcursor,
        int2* __restrict__ pairs, int E, int nbuck) {
    __shared__ int lcnt[256];
    __shared__ int lbase[256];
    int t = threadIdx.x;
    int base = blockIdx.x * 4096;
    if (t < nbuck) lcnt[t] = 0;
    __syncthreads();
    int d[16], s[16];
#pragma unroll
    for (int k = 0; k < 16; ++k) {
        int i = base + t + k * 256;
        if (i < E) {
            d[k] = dst[i];
            s[k] = src[i];
            atomicAdd(&lcnt[d[k] >> NBUCK_SHIFT], 1);
        } else {
            d[k] = -1;
            s[k] = 0;
        }
    }
    __syncthreads();
    if (t < nbuck) {
        int c = lcnt[t];
        int g = (c > 0) ? atomicAdd(&bcursor[t], c) : 0;
        lbase[t] = bbase[t] + g;
        lcnt[t] = 0;
    }
    __syncthreads();
#pragma unroll
    for (int k = 0; k < 16; ++k) {
        if (d[k] >= 0) {
            int b = d[k] >> NBUCK_SHIFT;
            int r = atomicAdd(&lcnt[b], 1);
            pairs[lbase[b] + r] = make_int2(s[k], d[k]);
        }
    }
}

// Phase D: per-bucket LDS histogram + scan -> row_ptr; scatter col within the bucket's
// contiguous window (L2-resident). One 1024-thread block per bucket.
__global__ __launch_bounds__(1024) void bucket_build_kernel(
        const int2* __restrict__ pairs, const int* __restrict__ bbase,
        int* __restrict__ row_ptr, int* __restrict__ col, int N, int E) {
    __shared__ int cnt[512];
    __shared__ int off[512];
    int t = threadIdx.x;
    int b = blockIdx.x;
    int s0 = bbase[b], s1 = bbase[b + 1];
    if (t < 512) cnt[t] = 0;
    __syncthreads();
    for (int i = s0 + t; i < s1; i += 1024)
        atomicAdd(&cnt[pairs[i].y & 511], 1);
    __syncthreads();
    int c = (t < 512) ? cnt[t] : 0;
    if (t < 512) off[t] = c;
    __syncthreads();
    for (int o = 1; o < 512; o <<= 1) {
        int y = (t < 512 && t >= o) ? off[t - o] : 0;
        __syncthreads();
        if (t < 512) off[t] += y;
        __syncthreads();
    }
    int v0 = b << NBUCK_SHIFT;
    if (t < 512) {
        int ex = off[t] - c;   // exclusive prefix within bucket
        off[t] = ex;
        cnt[t] = 0;
        if (v0 + t < N) row_ptr[v0 + t] = s0 + ex;
    }
    __syncthreads();
    for (int i = s0 + t; i < s1; i += 1024) {
        int2 p = pairs[i];
        int li = p.y & 511;
        int slot = s0 + off[li] + atomicAdd(&cnt[li], 1);
        col[slot] = p.x;
    }
    if (b == 0 && t == 0) row_ptr[N] = E;
}

// ---------------- dtype conversion ----------------
__global__ void f32_to_bf16_kernel(const float4* __restrict__ in, ushort4* __restrict__ out, int n4) {
    int i = blockIdx.x * blockDim.x + threadIdx.x;
    if (i < n4) {
        float4 f = in[i];
        ushort4 o;
        o.x = f2b(f.x); o.y = f2b(f.y); o.z = f2b(f.z); o.w = f2b(f.w);
        out[i] = o;
    }
}

// W[l][k][n] row-major -> frag-blocked bf16 for use as MFMA A-operand (swapped GEMM):
// flat short idx = ((l*32 + nt*4 + kb)*64 + lg*16 + l15)*8 + j holds W[k=kb*32+lg*8+j][n=nt*16+l15]
__global__ void wtrans_kernel(const float* __restrict__ W1, const float* __restrict__ W2,
                              unsigned short* __restrict__ W1L, unsigned short* __restrict__ W2L,
                              int total) {
    int i = blockIdx.x * blockDim.x + threadIdx.x;
    if (i < total) {
        int l = i >> 14;
        int rem = i & 16383;
        int k = rem >> 7;
        int n = rem & 127;
        int nt = n >> 4, l15 = n & 15;
        int kb = k >> 5, lg = (k >> 3) & 3, j = k & 7;
        int o = ((l * 32 + nt * 4 + kb) * 64 + lg * 16 + l15) * 8 + j;
        W1L[o] = f2b(W1[i]);
        W2L[o] = f2b(W2[i]);
    }
}

// ---------------- aggregation: rst[v] = h[v] + sum_{(u->v)} h[u] ----------------
// one wave per node; lane = j*16+i: i = feature block (8 bf16, 16B), j = edge slot.
// 4 independent acc chains -> up to 16 edges (64B/lane) in flight per iteration.
__global__ __launch_bounds__(256) void agg_kernel(
        const unsigned short* __restrict__ h, const int* __restrict__ row_ptr,
        const int* __restrict__ col, unsigned short* __restrict__ rst, int N) {
    int lane = threadIdx.x & 63;
    int i = lane & 15;
    int j = lane >> 4;
    int v = blockIdx.x * 4 + (threadIdx.x >> 6);
    if (v >= N) return;

    const unsigned short* hb = h + i * 8;
    int e0 = row_ptr[v], e1 = row_ptr[v + 1];

    float accA[8], accB[8], accC[8], accD[8];
#pragma unroll
    for (int r = 0; r < 8; ++r) { accA[r] = 0.f; accB[r] = 0.f; accC[r] = 0.f; accD[r] = 0.f; }

    if (j == 0) {
        u32x4 x = *(const u32x4*)(hb + (size_t)v * D);
        acc8(accA, x);
    }

    int e = e0 + j;
    for (; e + 12 < e1; e += 16) {
        int u0 = col[e];
        int u1 = col[e + 4];
        int u2 = col[e + 8];
        int u3 = col[e + 12];
        u32x4 x0 = *(const u32x4*)(hb + (size_t)u0 * D);
        u32x4 x1 = *(const u32x4*)(hb + (size_t)u1 * D);
        u32x4 x2 = *(const u32x4*)(hb + (size_t)u2 * D);
        u32x4 x3 = *(const u32x4*)(hb + (size_t)u3 * D);
        acc8(accA, x0);
        acc8(accB, x1);
        acc8(accC, x2);
        acc8(accD, x3);
    }
    for (; e + 4 < e1; e += 8) {
        int u0 = col[e];
        int u1 = col[e + 4];
        u32x4 x0 = *(const u32x4*)(hb + (size_t)u0 * D);
        u32x4 x1 = *(const u32x4*)(hb + (size_t)u1 * D);
        acc8(accA, x0);
        acc8(accB, x1);
    }
    if (e < e1) {
        u32x4 x0 = *(const u32x4*)(hb + (size_t)col[e] * D);
        acc8(accA, x0);
    }

    unsigned short outv[8];
#pragma unroll
    for (int r = 0; r < 8; ++r) {
        float s = (accA[r] + accB[r]) + (accC[r] + accD[r]);
        s += __shfl_xor(s, 16);
        s += __shfl_xor(s, 32);
        outv[r] = f2b(s);
    }
    if (j == 0) {
        u16x8_t o;
#pragma unroll
        for (int r = 0; r < 8; ++r) o[r] = outv[r];
        *(u16x8_t*)(rst + (size_t)v * D + i * 8) = o;
    }
}

// ---------------- fused MLP: one 16-node tile per wave (NO tile loop -> no spill) ----------------
// Swapped MFMA GEMMs (W frag-blocked in global as A-operand); h1 via per-wave padded LDS tile.
// Padded tile unit U(m,k) = (k/32)*80 + m*5 + (k%32)/8; shorts at U*8.
__global__ __launch_bounds__(256, 4) void mlp_kernel(
        const unsigned short* __restrict__ A, const unsigned short* __restrict__ W1L,
        const unsigned short* __restrict__ W2L, const float* __restrict__ b1,
        const float* __restrict__ b2, unsigned short* __restrict__ hOut,
        float* __restrict__ fOut, int mode, int ntiles, int N) {
    __shared__ float b1s[128], b2s[128];
    __shared__ unsigned short tilebuf[4 * 2560];
    int tid = threadIdx.x;
    if (tid < 128) b1s[tid] = b1[tid];
    else b2s[tid - 128] = b2[tid - 128];
    __syncthreads();
    int wave = tid >> 6, lane = tid & 63, l15 = lane & 15, lg = lane >> 4;
    unsigned short* buf = tilebuf + wave * 2560;
    int tile = blockIdx.x * 4 + wave;
    if (tile >= ntiles) return;
    int v0 = tile << 4;

    bf16x8 bfrag[4];
    const unsigned short* arow = A + (size_t)(v0 + l15) * D + lg * 8;
#pragma unroll
    for (int kb = 0; kb < 4; ++kb) bfrag[kb] = *(const bf16x8*)(arow + kb * 32);

    f32x4 acc[8];
#pragma unroll
    for (int nt = 0; nt < 8; ++nt) acc[nt] = (f32x4){0.f, 0.f, 0.f, 0.f};
#pragma unroll
    for (int kb = 0; kb < 4; ++kb)
#pragma unroll
        for (int nt = 0; nt < 8; ++nt) {
            bf16x8 wf = *(const bf16x8*)(W1L + ((nt * 4 + kb) * 64 + lane) * 8);
            acc[nt] = __builtin_amdgcn_mfma_f32_16x16x32_bf16(wf, bfrag[kb], acc[nt], 0, 0, 0);
        }
#pragma unroll
    for (int nt = 0; nt < 8; ++nt) {
        f32x4 bias = *(const f32x4*)(b1s + nt * 16 + lg * 4);
        int kb2 = nt >> 1;
        int lgk = (nt & 1) * 2 + (lg >> 1);
        int U = kb2 * 80 + l15 * 5 + lgk;
        u16x4_t o;
#pragma unroll
        for (int r = 0; r < 4; ++r) {
            float x = acc[nt][r] + bias[r];
            if (mode == 0) x = fmaxf(x, 0.f);
            o[r] = f2b(x);
        }
        *(u16x4_t*)(buf + U * 8 + (lg & 1) * 4) = o;
    }
    bf16x8 bf2[4];
#pragma unroll
    for (int kb = 0; kb < 4; ++kb)
        bf2[kb] = *(const bf16x8*)(buf + (kb * 80 + l15 * 5 + lg) * 8);
#pragma unroll
    for (int nt = 0; nt < 8; ++nt) acc[nt] = (f32x4){0.f, 0.f, 0.f, 0.f};
#pragma unroll
    for (int kb = 0; kb < 4; ++kb)
#pragma unroll
        for (int nt = 0; nt < 8; ++nt) {
            bf16x8 wf = *(const bf16x8*)(W2L + ((nt * 4 + kb) * 64 + lane) * 8);
            acc[nt] = __builtin_amdgcn_mfma_f32_16x16x32_bf16(wf, bf2[kb], acc[nt], 0, 0, 0);
        }
    int m = v0 + l15;
    if (m < N) {
#pragma unroll
        for (int nt = 0; nt < 8; ++nt) {
            f32x4 bias = *(const f32x4*)(b2s + nt * 16 + lg * 4);
            int c0 = nt * 16 + lg * 4;
            if (mode == 0) {
                u16x4_t o;
#pragma unroll
                for (int r = 0; r < 4; ++r) o[r] = f2b(fmaxf(acc[nt][r] + bias[r], 0.f));
                *(u16x4_t*)(hOut + (size_t)m * D + c0) = o;
            } else {
                f32x4 o;
#pragma unroll
                for (int r = 0; r < 4; ++r) o[r] = acc[nt][r] + bias[r];
                *(f32x4*)(fOut + (size_t)m * D + c0) = o;
            }
        }
    }
}

extern "C" void kernel_launch(void* const* d_in, const int* in_sizes, int n_in,
                              void* d_out, int out_size, void* d_ws, size_t ws_size,
                              hipStream_t stream) {
    const float* feat = (const float*)d_in[0];
    const float* W1 = (const float*)d_in[1];
    const float* b1 = (const float*)d_in[2];
    const float* W2 = (const float*)d_in[3];
    const float* b2 = (const float*)d_in[4];
    const int* src = (const int*)d_in[5];
    const int* dst = (const int*)d_in[6];

    const int N = in_sizes[0] / D;
    const int L = in_sizes[2] / D;
    const int E = in_sizes[5];

    char* w = (char*)d_ws;
    size_t off = 0;
    auto alloc = [&](size_t bytes) {
        void* p = w + off;
        off = (off + bytes + 255) & ~(size_t)255;
        return p;
    };
    unsigned short* bufA = (unsigned short*)alloc((size_t)N * D * 2);
    unsigned short* bufB = (unsigned short*)alloc((size_t)N * D * 2);
    size_t unionBytes = (size_t)N * D * 2;
    if ((size_t)E * 8 > unionBytes) unionBytes = (size_t)E * 8;
    unsigned short* bufR = (unsigned short*)alloc(unionBytes);   // agg out / pairs scratch
    int2* pairs = (int2*)bufR;
    int* col = (int*)alloc((size_t)E * 4);
    int* row_ptr = (int*)alloc((size_t)(N + 1) * 4);
    int* bco = (int*)alloc(512 * 4);       // bco[256] + bcursor[256]
    int* bcursor = bco + 256;
    int* bbase = (int*)alloc(257 * 4);
    unsigned short* W1L = (unsigned short*)alloc((size_t)L * 16384 * 2);
    unsigned short* W2L = (unsigned short*)alloc((size_t)L * 16384 * 2);

    int nbuck = (N + (1 << NBUCK_SHIFT) - 1) >> NBUCK_SHIFT;

    // CSR build — bucket-local
    hipMemsetAsync(bco, 0, 512 * 4, stream);
    coarse_hist_kernel<<<512, 256, 0, stream>>>(dst, bco, E, nbuck);
    bucket_scan_kernel<<<1, 256, 0, stream>>>(bco, bbase, nbuck, E);
    bucket_kernel<<<(E + 4095) / 4096, 256, 0, stream>>>(src, dst, bbase, bcursor, pairs, E, nbuck);
    bucket_build_kernel<<<nbuck, 1024, 0, stream>>>(pairs, bbase, row_ptr, col, N, E);

    // dtype prep
    int n4 = N * D / 4;
    f32_to_bf16_kernel<<<(n4 + 255) / 256, 256, 0, stream>>>((const float4*)feat, (ushort4*)bufA, n4);
    int wtotal = L * D * D;
    wtrans_kernel<<<(wtotal + 255) / 256, 256, 0, stream>>>(W1, W2, W1L, W2L, wtotal);

    int ntiles = (N + 15) / 16;
    int aggBlocks = (N + 3) / 4;
    int mlpGrid = (ntiles + 3) / 4;
    const unsigned short* hin[3] = {bufA, bufB, bufA};
    unsigned short* hout[3] = {bufB, bufA, nullptr};
    for (int i = 0; i < L; ++i) {
        int mode = (i == L - 1) ? 1 : 0;
        agg_kernel<<<aggBlocks, 256, 0, stream>>>(hin[i], row_ptr, col, bufR, N);
        mlp_kernel<<<mlpGrid, 256, 0, stream>>>(bufR, W1L + (size_t)i * 16384, W2L + (size_t)i * 16384,
                                                b1 + i * D, b2 + i * D, hout[i], (float*)d_out,
                                                mode, ntiles, N);
    }
}